// Round 1
// 467.590 us; speedup vs baseline: 1.0870x; 1.0870x over previous
//
#include <hip/hip_runtime.h>
#include <stdint.h>

typedef __attribute__((ext_vector_type(8))) short bf16x8;
typedef __attribute__((ext_vector_type(4))) float f32x4;
typedef unsigned short u16;
typedef __attribute__((ext_vector_type(4))) unsigned short us4;
typedef __attribute__((ext_vector_type(8))) unsigned short us8;

#define NP 80   // xT node-dim stride (x transposed: [feat][node]); stride 160B -> bank-uniform b128 reads

__device__ __constant__ int c_RS[9] = {0, 17, 22, 27, 31, 36, 42, 48, 60};
__device__ __constant__ int c_RE[9] = {16, 21, 26, 30, 35, 41, 47, 59, 67};

__device__ __forceinline__ float b2f(u16 h) {
    union { unsigned int u; float f; } v;
    v.u = ((unsigned int)h) << 16;
    return v.f;
}
__device__ __forceinline__ u16 f2b(float f) {
    union { float f; unsigned int u; } v;
    v.f = f;
    unsigned int r = v.u + 0x7fffu + ((v.u >> 16) & 1u);  // RNE
    return (u16)(r >> 16);
}
// ag: [node][feat] bf16, stride 128, XOR-swizzled: idx bits 4,5 ^= row bits 2,3.
// Swizzle permutes within a 128-u16 row (conflict-free scattered u16 C-writes:
// qd spreads rows' bits2,3 -> 4 bank groups; b128 reads stay uniform 8 lanes/slot).
__device__ __forceinline__ int agx(int row, int col) {
    return row * 128 + (col ^ (((row & 4) << 3) | ((row & 8) << 1)));
}

// Prep: packed-K adjacency adjp[80][96] bf16: cols 0..63 = adj cols 0..63,
// cols 64..79 = 0, cols 80..95 = adj cols 64..79. GEMM1 K-step 2 pairs A cols
// 64..95 with B nodes 48..79, so sum == sum_{k<80} adj[m][k]*x[k] with only
// 16x16x32 MFMAs and xT node extent 80. Rows/cols >=77 are zero (annihilate pad).
// WT: W0..W3 (f32 [k][n]) -> bf16 WT[l][n][k] for direct B-fragment loads.
__global__ void prep_kernel(const float* __restrict__ adj,
                            const float* __restrict__ W0, const float* __restrict__ W1,
                            const float* __restrict__ W2, const float* __restrict__ W3,
                            u16* __restrict__ adjp, u16* __restrict__ WT) {
    int id = blockIdx.x * 256 + threadIdx.x;  // grid = 256*256 = 65536
    if (id < 80 * 96) {
        int m = id / 96, c = id - m * 96;
        float v = 0.f;
        if (m < 77) {
            int k = (c < 64) ? c : (c - 16);
            if (c >= 64 && c < 80) k = 77;   // zero block
            if (k < 77) v = adj[m * 77 + k];
        }
        adjp[id] = f2b(v);
    }
    {
        int l = id >> 14, r = id & 16383;
        int n = r >> 7, k = r & 127;
        const float* W = (l == 0) ? W0 : (l == 1) ? W1 : (l == 2) ? W2 : W3;
        WT[id] = f2b(W[k * 128 + n]);
    }
}

__global__ __launch_bounds__(256, 4) void gcn_kernel(
    const float* __restrict__ lm, const float* __restrict__ Wr,
    const float* __restrict__ b0, const float* __restrict__ b1,
    const float* __restrict__ b2, const float* __restrict__ b3,
    const float* __restrict__ gamma, const float* __restrict__ beta,
    const u16* __restrict__ adjp, const u16* __restrict__ WT,
    float* __restrict__ out) {
    // LDS exactly 40960 B -> 4 blocks/CU (163840/40960 = 4), 16 waves/CU.
    __shared__ __align__(16) u16 xT[128 * NP];   // 20480 B: x^T [feat][node 0..79]
    __shared__ __align__(16) u16 ag[80 * 128];   // 20480 B: [node][feat], swizzled

    const int t = threadIdx.x;
    const int lane = t & 63;
    const int w = t >> 6;        // wave 0..3; wave owns feat-tiles tn = {w, w+4}
    const int lo = lane & 15;
    const int qd = lane >> 4;
    const size_t pos = blockIdx.x;
    const float* lmp = lm + pos * (68 * 128);

    // scratch aliased into dead LDS regions:
    float* WrF = (float*)&ag[68 * 128];      // ag rows 68-69 (lm only fills rows 0..67)
    float* scoreS = (float*)&ag[70 * 128];   // ag rows 70-71; dead before first C-write
    float* muP = (float*)xT;                 // xT dead after layer-3 GEMM1
    float* rsP = muP + 80;

    // ---- phase 0: stage lm f32 -> bf16 into ag; Wr -> scratch; zero xT pad cols ----
    if (t < 128) {
        WrF[t] = Wr[t];
        xT[t * NP + 77] = 0; xT[t * NP + 78] = 0; xT[t * NP + 79] = 0;
    }
    const float4* lmp4 = (const float4*)lmp;
    for (int c = t; c < 68 * 32; c += 256) {     // 32 float4-chunks per node
        int n = c >> 5, q = c & 31;
        float4 v = lmp4[c];
        us4 o;
        o[0] = f2b(v.x); o[1] = f2b(v.y); o[2] = f2b(v.z); o[3] = f2b(v.w);
        *(us4*)(&ag[agx(n, q * 4)]) = o;
    }
    __syncthreads();

    // ---- A2: LDS transpose ag -> xT cols 0..67 ; B1: region-pool scores ----
    for (int c = t; c < 68 * 16; c += 256) {
        int d8 = c / 68, n = c - d8 * 68;
        us8 v = *(const us8*)(&ag[agx(n, d8 * 8)]);
#pragma unroll
        for (int j = 0; j < 8; j++) xT[(d8 * 8 + j) * NP + n] = v[j];
    }
    if (t < 68) {   // br is a constant shift -> cancels in softmax
        float s = 0.f;
        for (int d8 = 0; d8 < 16; d8++) {
            us8 v = *(const us8*)(&ag[agx(t, d8 * 8)]);
#pragma unroll
            for (int j = 0; j < 8; j++) s += b2f(v[j]) * WrF[d8 * 8 + j];
        }
        scoreS[t] = s;
    }
    __syncthreads();

    // ---- B3: pooled global nodes (softmax recomputed per thread; kills the
    //      9-thread serial phase + one barrier) -> xT cols 68..76 ----
    for (int c = t; c < 9 * 128; c += 256) {
        int r = c >> 7, d = c & 127;
        int s0 = c_RS[r], e0 = c_RE[r];
        float mx = -3e38f;
        for (int i = s0; i <= e0; i++) mx = fmaxf(mx, scoreS[i]);
        float sum = 0.f, g = 0.f;
        for (int i = s0; i <= e0; i++) {
            float e = __expf(scoreS[i] - mx);
            sum += e;
            g += e * b2f(ag[agx(i, d)]);
        }
        xT[d * NP + 68 + r] = f2b(g / sum);
    }
    __syncthreads();

    // ---- 4-layer GCN: agg = adj@x (MFMA), out = relu(agg@W + b) [+ x] ----
    for (int l = 0; l < 4; l++) {
        f32x4 acc[5][2];
#pragma unroll
        for (int a = 0; a < 5; a++)
#pragma unroll
            for (int j = 0; j < 2; j++)
#pragma unroll
                for (int r = 0; r < 4; r++) acc[a][j][r] = 0.f;
        // step 1: agg = adjp(80x96 packed-K) @ x(80x128); A global (L1-hot), B from xT
#pragma unroll
        for (int ks = 0; ks < 3; ks++) {
            const int koff = (ks == 2) ? 48 : ks * 32;   // B node offsets {0,32,48}
            bf16x8 bA[5], bB[2];
#pragma unroll
            for (int tm = 0; tm < 5; tm++)
                bA[tm] = *(const bf16x8*)(adjp + (tm * 16 + lo) * 96 + ks * 32 + qd * 8);
#pragma unroll
            for (int j = 0; j < 2; j++)
                bB[j] = *(const bf16x8*)(&xT[((w + 4 * j) * 16 + lo) * NP + koff + qd * 8]);
#pragma unroll
            for (int tm = 0; tm < 5; tm++)
#pragma unroll
                for (int j = 0; j < 2; j++)
                    acc[tm][j] = __builtin_amdgcn_mfma_f32_16x16x32_bf16(bA[tm], bB[j], acc[tm][j], 0, 0, 0);
        }
        // C layout (m89): col = lane&15, row = qd*4 + reg -> swizzled row-major write
#pragma unroll
        for (int tm = 0; tm < 5; tm++)
#pragma unroll
            for (int j = 0; j < 2; j++) {
                int col = (w + 4 * j) * 16 + lo;
#pragma unroll
                for (int r = 0; r < 4; r++)
                    ag[agx(tm * 16 + qd * 4 + r, col)] = f2b(acc[tm][j][r]);
            }
        __syncthreads();

        // step 2: out = agg(80x128) @ W(128x128); A from ag, B from WT (global)
#pragma unroll
        for (int a = 0; a < 5; a++)
#pragma unroll
            for (int j = 0; j < 2; j++)
#pragma unroll
                for (int r = 0; r < 4; r++) acc[a][j][r] = 0.f;
        const u16* WTl = WT + l * 16384;
#pragma unroll
        for (int ks = 0; ks < 4; ks++) {
            bf16x8 aF[5], bW[2];
#pragma unroll
            for (int tm = 0; tm < 5; tm++)
                aF[tm] = *(const bf16x8*)(&ag[agx(tm * 16 + lo, ks * 32 + qd * 8)]);
#pragma unroll
            for (int j = 0; j < 2; j++)
                bW[j] = *(const bf16x8*)(WTl + ((w + 4 * j) * 16 + lo) * 128 + ks * 32 + qd * 8);
#pragma unroll
            for (int tm = 0; tm < 5; tm++)
#pragma unroll
                for (int j = 0; j < 2; j++)
                    acc[tm][j] = __builtin_amdgcn_mfma_f32_16x16x32_bf16(aF[tm], bW[j], acc[tm][j], 0, 0, 0);
        }
        const float* bl = (l == 0) ? b0 : (l == 1) ? b1 : (l == 2) ? b2 : b3;
        if (l == 3) __syncthreads();  // all waves done reading ag before overwrite
        // epilogue: bias + relu (+ residual from xT), packed us4 RMW (rows contiguous)
#pragma unroll
        for (int j = 0; j < 2; j++) {
            int col = (w + 4 * j) * 16 + lo;
            float bv = bl[col];          // global, L2/L1-hot (same 512B for all blocks)
            if (l < 3) {
#pragma unroll
                for (int tm = 0; tm < 5; tm++) {
                    int nb = tm * 16 + qd * 4;
                    us4 old4 = *(const us4*)(&xT[col * NP + nb]);
                    us4 nv;
#pragma unroll
                    for (int r = 0; r < 4; r++) {
                        float v = fmaxf(acc[tm][j][r] + bv, 0.f) + b2f(old4[r]);
                        nv[r] = f2b(v);
                    }
                    *(us4*)(&xT[col * NP + nb]) = nv;   // residual == current x, same cols
                }
            } else {
#pragma unroll
                for (int tm = 0; tm < 5; tm++)
#pragma unroll
                    for (int r = 0; r < 4; r++)
                        ag[agx(tm * 16 + qd * 4 + r, col)] = f2b(fmaxf(acc[tm][j][r] + bv, 0.f));
            }
        }
        __syncthreads();
    }

    // ---- LayerNorm stats: 2 threads per node, pair-combine via shfl ----
    if (t < 154) {
        int n = t >> 1, h = t & 1;
        float s = 0.f, ss = 0.f;
#pragma unroll
        for (int i = 0; i < 8; i++) {
            us8 v = *(const us8*)(&ag[agx(n, h * 64 + i * 8)]);
#pragma unroll
            for (int j = 0; j < 8; j++) { float a = b2f(v[j]); s += a; ss += a * a; }
        }
        s += __shfl_xor(s, 1);
        ss += __shfl_xor(ss, 1);
        if (h == 0) {
            float mu = s * (1.f / 128.f);
            muP[n] = mu;
            rsP[n] = rsqrtf(ss * (1.f / 128.f) - mu * mu + 1e-5f);
        }
    }
    __syncthreads();

    // ---- normalize + coalesced f32 store; gamma/beta straight from global (L1-hot) ----
    float* outp = out + pos * 9856;
    for (int c = t; c < 77 * 32; c += 256) {
        int n = c >> 5, q = c & 31;
        us4 v = *(const us4*)(&ag[agx(n, q * 4)]);
        float mu = muP[n], rs = rsP[n];
        float4 gm = *(const float4*)(gamma + q * 4);
        float4 bt = *(const float4*)(beta + q * 4);
        float4 o;
        o.x = (b2f(v[0]) - mu) * rs * gm.x + bt.x;
        o.y = (b2f(v[1]) - mu) * rs * gm.y + bt.y;
        o.z = (b2f(v[2]) - mu) * rs * gm.z + bt.z;
        o.w = (b2f(v[3]) - mu) * rs * gm.w + bt.w;
        *(float4*)(outp + n * 128 + q * 4) = o;
    }
}

extern "C" void kernel_launch(void* const* d_in, const int* in_sizes, int n_in,
                              void* d_out, int out_size, void* d_ws, size_t ws_size,
                              hipStream_t stream) {
    const float* lm = (const float*)d_in[0];
    const float* adj = (const float*)d_in[1];
    const float* Wr = (const float*)d_in[2];
    // d_in[3] = br: constant shift inside softmax -> cancels, unused
    const float* W0 = (const float*)d_in[4];
    const float* b0 = (const float*)d_in[5];
    const float* W1 = (const float*)d_in[6];
    const float* b1 = (const float*)d_in[7];
    const float* W2 = (const float*)d_in[8];
    const float* b2 = (const float*)d_in[9];
    const float* W3 = (const float*)d_in[10];
    const float* b3 = (const float*)d_in[11];
    const float* gamma = (const float*)d_in[12];
    const float* beta = (const float*)d_in[13];

    u16* adjp = (u16*)d_ws;                            // 80*96*2 = 15,360 B
    u16* WT = (u16*)((char*)d_ws + 80 * 96 * 2);       // 4*128*128*2 = 131,072 B

    prep_kernel<<<256, 256, 0, stream>>>(adj, W0, W1, W2, W3, adjp, WT);
    gcn_kernel<<<4096, 256, 0, stream>>>(lm, Wr, b0, b1, b2, b3, gamma, beta,
                                         adjp, WT, (float*)d_out);
}